// Round 9
// baseline (1012.209 us; speedup 1.0000x reference)
//
#include <hip/hip_runtime.h>

#define HH 80
#define WW 80
#define NPIX 6400
#define PW 82
#define NPP (PW*PW)        // 6724 padded pixels
#define CFE 64
#define CMA 3
#define KF 576
#define GUARD 1024
#define NREG 8

#define PA 1024            // S0 row window per block (incl. 84+84 halo)
#define POUT 856           // output rows per block
#define BW 1056            // B row window = PA + 32

typedef unsigned long long u64;
typedef unsigned int u32;

// 16B load with only 4B alignment guarantee
struct f4u { float x, y, z, w; };

__device__ __forceinline__ void gload4(const float* g, float* l) {
    __builtin_amdgcn_global_load_lds((const __attribute__((address_space(1))) void*)g,
                                     (__attribute__((address_space(3))) void*)l, 4, 0, 0);
}
__device__ __forceinline__ float4 ld4(const float* p) { return *(const float4*)p; }

// ---------------------------------------------------------------------------
// per-pixel channel sum-of-squares (style side only), real grid
// ---------------------------------------------------------------------------
__global__ __launch_bounds__(256)
void pixsq_kernel(const float* __restrict__ sf, const float* __restrict__ sm,
                  float* __restrict__ psf, float* __restrict__ psm) {
    int g = blockIdx.x * 256 + threadIdx.x;
    if (g >= 2 * NPIX) return;
    int b = g / NPIX, m = g - b * NPIX;
    const float* p = sf + (size_t)b * CFE * NPIX + m;
    float a = 0.f;
    #pragma unroll 8
    for (int c = 0; c < CFE; ++c) { float v = p[c * NPIX]; a = fmaf(v, v, a); }
    const float* q = sm + (size_t)b * CMA * NPIX + m;
    float am = 0.f;
    #pragma unroll
    for (int c = 0; c < CMA; ++c) { float v = q[c * NPIX]; am = fmaf(v, v, am); }
    psf[g] = a; psm[g] = am;
}

// 9-tap masked patch-norms -> combined reciprocal, PADDED layout (0 = invalid)
__global__ __launch_bounds__(256)
void rn2_kernel(const float* __restrict__ psf, const float* __restrict__ psm,
                float* __restrict__ rn2p) {
    int g = blockIdx.x * 256 + threadIdx.x;
    if (g >= 2 * NPIX) return;
    int b = g / NPIX, m = g - b * NPIX;
    int mh = m / WW, mw = m - mh * WW;
    float sF = 0.f, sM = 0.f;
    #pragma unroll
    for (int di = -1; di <= 1; ++di) {
        if ((unsigned)(mh + di) >= HH) continue;
        #pragma unroll
        for (int dj = -1; dj <= 1; ++dj) {
            if ((unsigned)(mw + dj) >= WW) continue;
            int mm = m + di * WW + dj;
            sF += psf[b * NPIX + mm];
            sM += psm[b * NPIX + mm];
        }
    }
    float rf = 1.f / fmaxf(sqrtf(sF), 1e-12f);
    float rm = 1.f / fmaxf(sqrtf(sM), 1e-12f);
    rn2p[(size_t)b * NPP + (mh + 1) * PW + (mw + 1)] = rf * rm;
}

// ---------------------------------------------------------------------------
// Build zero-padded 82x82 copies (borders pre-zeroed by the memset).
// ---------------------------------------------------------------------------
__global__ __launch_bounds__(256)
void pad_kernel(const float* __restrict__ cf, const float* __restrict__ sf,
                const float* __restrict__ cm, const float* __restrict__ sm,
                float* __restrict__ cfp, float* __restrict__ sfp,
                float* __restrict__ cmp, float* __restrict__ smp) {
    int gid = blockIdx.x * 256 + threadIdx.x;
    if (gid >= 2 * 2 * 67 * NPIX) return;
    int pix = gid % NPIX; int t = gid / NPIX;
    int c = t % 67; t /= 67;
    int b = t & 1; int which = t >> 1;
    int h = pix / WW, w = pix - h * WW;
    int qq = (h + 1) * PW + (w + 1);
    if (which == 0) {
        if (c < 64) cfp[((size_t)b * CFE + c) * NPP + qq] = cf[((size_t)b * CFE + c) * NPIX + pix];
        else        cmp[((size_t)b * CMA + (c - 64)) * NPP + qq] = cm[((size_t)b * CMA + (c - 64)) * NPIX + pix];
    } else {
        if (c < 64) sfp[((size_t)b * CFE + c) * NPP + qq] = sf[((size_t)b * CFE + c) * NPIX + pix];
        else        smp[((size_t)b * CMA + (c - 64)) * NPP + qq] = sm[((size_t)b * CMA + (c - 64)) * NPIX + pix];
    }
}

// ---------------------------------------------------------------------------
// Fused kernel, 1024 threads (16 waves/CU). A-operand from global->regs,
// B from LDS; swizzled S0 buffer; sliding-window taps (8 rows x 4 d / thread).
// ---------------------------------------------------------------------------
__global__ __launch_bounds__(1024, 4)
void fuse_kernel(const float* __restrict__ cfp, const float* __restrict__ sfp,
                 const float* __restrict__ cmp, const float* __restrict__ smp,
                 const float* __restrict__ rn2p, u64* __restrict__ pbest) {
    const int pt = blockIdx.y;
    const int b  = blockIdx.z;
    const int pstart = 83 + POUT * pt;
    const int pend   = min(pstart + POUT, 6641);
    const int pbase  = pstart - 84;
    const int dte0   = (6644 - pend) >> 5;
    const int dtemax = (13200 - pstart) >> 5;
    const int dte = dte0 + blockIdx.x;
    if (dte > dtemax) return;
    const int d0 = -6560 + 32 * dte;

    __shared__ float pool[PA * 36];              // 147456 B (staging aliases S0)

    const int tid = threadIdx.x;
    const int tp = tid & 255;                    // GEMM row group (4 rows)
    const int tg = tid >> 8;                     // GEMM d group (8 cols), 0..3
    const int wb = tid & 960;                    // wave-uniform LDS float offset
    const int swz = (tp & 7) << 2;

    const float* Aglob = cfp + (size_t)b * CFE * NPP + pbase + 4 * tp;
    const float* Bglob = sfp + (size_t)b * CFE * NPP + pbase + d0;
    const float* AglobM = cmp + (size_t)b * CMA * NPP + pbase + 4 * tp;
    const float* BglobM = smp + (size_t)b * CMA * NPP + pbase + d0;

    float acc[4][8];
    float pdF[8][4], pdM[8][4];

    auto zacc = [&]() {
        #pragma unroll
        for (int k = 0; k < 4; ++k)
            #pragma unroll
            for (int j = 0; j < 8; ++j) acc[k][j] = 0.f;
    };

    // stage one 8-channel B chunk (BW rows) into dbuf half
    auto stageB = [&](int q, int buf) {
        float* Bb = pool + buf * (8 * BW);
        const float* Bs = Bglob + (size_t)(q * 8) * NPP;
        #pragma unroll
        for (int cc = 0; cc < 8; ++cc) {
            gload4(Bs + cc * NPP + tid, Bb + cc * BW + wb);
            if (tid < 32) gload4(Bs + cc * NPP + 1024 + tid, Bb + cc * BW + 1024);
        }
    };

    // one channel: acc[k][j] += A(reg)[k] * B_lds[4tp+k + 8tg+j]
    auto gemmc1 = [&](const f4u& a4, const float* Bb) {
        const float* Br = Bb + 4 * tp + 8 * tg;
        float bb[12];
        *(float4*)bb       = ld4(Br);
        *(float4*)(bb + 4) = ld4(Br + 4);
        *(float4*)(bb + 8) = ld4(Br + 8);
        const float a[4] = {a4.x, a4.y, a4.z, a4.w};
        #pragma unroll
        for (int k = 0; k < 4; ++k)
            #pragma unroll
            for (int j = 0; j < 8; ++j)
                acc[k][j] = fmaf(a[k], bb[k + j], acc[k][j]);
    };

    // acc -> S0 LDS [PA rows][32 d], row stride 36, XOR-swizzled positions
    auto s0write = [&]() {
        #pragma unroll
        for (int k = 0; k < 4; ++k) {
            float* dr = pool + (4 * tp + k) * 36;
            *(float4*)(dr + ((8 * tg) ^ swz)) =
                make_float4(acc[k][0], acc[k][1], acc[k][2], acc[k][3]);
            *(float4*)(dr + ((8 * tg + 4) ^ swz)) =
                make_float4(acc[k][4], acc[k][5], acc[k][6], acc[k][7]);
        }
    };

    // sliding-window 9-tap stencil: thread (tid<856) owns 8 rows x 4 d
    auto tapsrun = [&](float (&pd)[8][4]) {
        if (tid >= 856) return;
        const int rg = tid >> 3, dg = tid & 7;
        const int p0w = 84 + 8 * rg;             // first output row (window coords)
        #pragma unroll
        for (int k = 0; k < 8; ++k)
            #pragma unroll
            for (int j = 0; j < 4; ++j) pd[k][j] = 0.f;
        static const int dg3[3] = {-82, 0, 82};
        #pragma unroll
        for (int g = 0; g < 3; ++g) {
            float4 w[10];
            #pragma unroll
            for (int r = 0; r < 10; ++r) {
                const int rr = p0w + dg3[g] - 1 + r;
                const int sw = ((rr >> 2) & 7) << 2;
                w[r] = ld4(pool + rr * 36 + ((4 * dg) ^ sw));
            }
            #pragma unroll
            for (int k = 0; k < 8; ++k) {
                pd[k][0] += w[k].x + w[k + 1].x + w[k + 2].x;
                pd[k][1] += w[k].y + w[k + 1].y + w[k + 2].y;
                pd[k][2] += w[k].z + w[k + 1].z + w[k + 2].z;
                pd[k][3] += w[k].w + w[k + 1].w + w[k + 2].w;
            }
        }
    };

    // ---- feature correlation: 8 chunks of 8 channels; B dbuf LDS, A reg ping-pong
    zacc();
    f4u A0[4], A1[4];
    #pragma unroll
    for (int c = 0; c < 4; ++c) A0[c] = *(const f4u*)(Aglob + (size_t)c * NPP);
    stageB(0, 0);
    __syncthreads();
    #pragma unroll 1
    for (int q = 0; q < 8; ++q) {
        const int buf = q & 1;
        if (q < 7) stageB(q + 1, buf ^ 1);
        #pragma unroll
        for (int c = 0; c < 4; ++c) A1[c] = *(const f4u*)(Aglob + (size_t)(q * 8 + 4 + c) * NPP);
        const float* Bb = pool + buf * (8 * BW);
        #pragma unroll
        for (int c = 0; c < 4; ++c) gemmc1(A0[c], Bb + c * BW);
        if (q < 7) {
            #pragma unroll
            for (int c = 0; c < 4; ++c) A0[c] = *(const f4u*)(Aglob + (size_t)((q + 1) * 8 + c) * NPP);
        }
        #pragma unroll
        for (int c = 0; c < 4; ++c) gemmc1(A1[c], Bb + (4 + c) * BW);
        __syncthreads();
    }
    s0write();
    __syncthreads();
    tapsrun(pdF);
    __syncthreads();

    // ---- mask correlation: 3 channels; B staged once, A from global regs
    f4u Am[3];
    #pragma unroll
    for (int c = 0; c < 3; ++c) {
        Am[c] = *(const f4u*)(AglobM + (size_t)c * NPP);
        gload4(BglobM + (size_t)c * NPP + tid, pool + c * BW + wb);
        if (tid < 32) gload4(BglobM + (size_t)c * NPP + 1024 + tid, pool + c * BW + 1024);
    }
    __syncthreads();
    zacc();
    #pragma unroll
    for (int c = 0; c < 3; ++c) gemmc1(Am[c], pool + c * BW);
    __syncthreads();
    s0write();
    __syncthreads();
    tapsrun(pdM);

    // ---- score + per-row argmax: reduce across 8 dg lanes, then atomicMax
    if (tid < 856) {
        const int rg = tid >> 3, dg = tid & 7;
        const float* rb = rn2p + (size_t)b * NPP;
        u64* pb = pbest + ((size_t)(dte & (NREG - 1)) * 2 + b) * NPIX;
        #pragma unroll
        for (int k = 0; k < 8; ++k) {
            const int row = 84 + 8 * rg + k;
            const int p = pbase + row;
            const int ph = p / PW, pw2 = p - ph * PW;
            const bool ok = (p < pend) && (ph >= 1) && (ph <= 80) && (pw2 >= 1) && (pw2 <= 80);
            u64 key = 0;
            if (ok) {
                #pragma unroll
                for (int j = 0; j < 4; ++j) {
                    int mp = p + d0 + 4 * dg + j;
                    if ((unsigned)mp >= (unsigned)NPP) continue;
                    float r2 = rb[mp];
                    if (r2 == 0.f) continue;               // pad/border -> invalid m
                    float sc = pdF[k][j] * pdM[k][j] * r2;
                    sc += 0.f;                             // -0 -> +0
                    u32 u = __float_as_uint(sc);
                    u ^= (u >> 31) ? 0xFFFFFFFFu : 0x80000000u;
                    u64 k2 = ((u64)u << 32) | (u32)~(u32)mp;
                    if (k2 > key) key = k2;
                }
            }
            u64 o;
            o = __shfl_xor(key, 1); if (o > key) key = o;
            o = __shfl_xor(key, 2); if (o > key) key = o;
            o = __shfl_xor(key, 4); if (o > key) key = o;
            if (dg == 0 && key) {
                const int n_real = (ph - 1) * 80 + (pw2 - 1);
                u64 cur = pb[n_real];                      // monotone -> safe filter
                if (key > cur) atomicMax(&pb[n_real], key);
            }
        }
    }
}

// ---------------------------------------------------------------------------
// Reduce the NREG region keys + gather the winning style patch per n.
// ---------------------------------------------------------------------------
__global__ __launch_bounds__(64)
void gather_kernel(const float* __restrict__ sf, const u64* __restrict__ pbest,
                   float* __restrict__ out) {
    int n = blockIdx.x, b = blockIdx.y;
    int lane = threadIdx.x;

    u64 key = 0;
    #pragma unroll
    for (int r = 0; r < NREG; ++r) {
        u64 k = pbest[((size_t)r * 2 + b) * NPIX + n];
        if (k > key) key = k;
    }
    int mp = (int)(~(u32)key);
    int m = 0;
    if ((unsigned)mp < (unsigned)NPP) {
        int ph = mp / PW, pw = mp - ph * PW;
        if (ph >= 1 && ph <= 80 && pw >= 1 && pw <= 80)
            m = (ph - 1) * 80 + (pw - 1);
    }
    int mh = m / WW, mw = m - mh * WW;
    const float* sfb = sf + (size_t)b * CFE * NPIX;
    float* ob = out + ((size_t)b * NPIX + n) * (size_t)KF;
    #pragma unroll
    for (int e = lane; e < KF; e += 64) {
        int c = e / 9, pos = e - c * 9;
        int di = pos / 3 - 1, dj = pos - (pos / 3) * 3 - 1;
        int h = mh + di, w = mw + dj;
        ob[e] = ((unsigned)h < HH && (unsigned)w < WW) ? sfb[c * NPIX + h * WW + w] : 0.f;
    }
}

// ---------------------------------------------------------------------------
extern "C" void kernel_launch(void* const* d_in, const int* in_sizes, int n_in,
                              void* d_out, int out_size, void* d_ws, size_t ws_size,
                              hipStream_t stream) {
    const float* cf = (const float*)d_in[0];
    const float* sf = (const float*)d_in[1];
    const float* cm = (const float*)d_in[2];
    const float* sm = (const float*)d_in[3];
    float* out = (float*)d_out;

    // ws layout (floats)
    float* psf = (float*)d_ws;                          // 2*NPIX
    float* psm = psf + 2 * NPIX;                        // 2*NPIX
    u64*  pbest = (u64*)(psm + 2 * NPIX);               // NREG*2*NPIX u64
    float* rn2p = (float*)(pbest + (size_t)NREG * 2 * NPIX);  // 2*NPP
    float* padreg = rn2p + 2 * NPP;                     // GUARD
    float* cfp = padreg + GUARD;                        // 2*64*NPP
    float* sfp = cfp + (size_t)2 * CFE * NPP + GUARD;   // 2*64*NPP
    float* cmp = sfp + (size_t)2 * CFE * NPP + GUARD;   // 2*3*NPP
    float* smp = cmp + (size_t)2 * CMA * NPP + GUARD;   // 2*3*NPP (+ trailing GUARD)

    // zero pbest + rn2p + all padded arrays + guards in one contiguous shot
    size_t zero_bytes = (size_t)NREG * 2 * NPIX * 8 +
        ((size_t)2 * NPP + (size_t)5 * GUARD +
         (size_t)4 * CFE * NPP + (size_t)4 * CMA * NPP) * 4;
    hipMemsetAsync(pbest, 0, zero_bytes, stream);

    pad_kernel<<<(2 * 2 * 67 * NPIX + 255) / 256, 256, 0, stream>>>(
        cf, sf, cm, sm, cfp, sfp, cmp, smp);
    pixsq_kernel<<<(2 * NPIX + 255) / 256, 256, 0, stream>>>(sf, sm, psf, psm);
    rn2_kernel  <<<(2 * NPIX + 255) / 256, 256, 0, stream>>>(psf, psm, rn2p);

    fuse_kernel<<<dim3(232, 8, 2), 1024, 0, stream>>>(cfp, sfp, cmp, smp, rn2p, pbest);

    gather_kernel<<<dim3(NPIX, 2), 64, 0, stream>>>(sf, pbest, out);
}

// Round 11
// 810.762 us; speedup vs baseline: 1.2485x; 1.2485x over previous
//
#include <hip/hip_runtime.h>

#define HH 80
#define WW 80
#define NPIX 6400
#define PW 82
#define NPP (PW*PW)        // 6724 padded pixels
#define CFE 64
#define CMA 3
#define KF 576
#define GUARD 1024
#define NREG 8

#define PA 1024            // S0 row window per block (incl. 84+84 halo)
#define POUT 856           // output rows per block
#define BW 1056            // B row window = PA + 32

typedef unsigned long long u64;
typedef unsigned int u32;

__device__ __forceinline__ void gload4(const float* g, float* l) {
    __builtin_amdgcn_global_load_lds((const __attribute__((address_space(1))) void*)g,
                                     (__attribute__((address_space(3))) void*)l, 4, 0, 0);
}
__device__ __forceinline__ float4 ld4(const float* p) { return *(const float4*)p; }

// ---------------------------------------------------------------------------
// per-pixel channel sum-of-squares (style side only), real grid
// ---------------------------------------------------------------------------
__global__ __launch_bounds__(256)
void pixsq_kernel(const float* __restrict__ sf, const float* __restrict__ sm,
                  float* __restrict__ psf, float* __restrict__ psm) {
    int g = blockIdx.x * 256 + threadIdx.x;
    if (g >= 2 * NPIX) return;
    int b = g / NPIX, m = g - b * NPIX;
    const float* p = sf + (size_t)b * CFE * NPIX + m;
    float a = 0.f;
    #pragma unroll 8
    for (int c = 0; c < CFE; ++c) { float v = p[c * NPIX]; a = fmaf(v, v, a); }
    const float* q = sm + (size_t)b * CMA * NPIX + m;
    float am = 0.f;
    #pragma unroll
    for (int c = 0; c < CMA; ++c) { float v = q[c * NPIX]; am = fmaf(v, v, am); }
    psf[g] = a; psm[g] = am;
}

// 9-tap masked patch-norms -> combined reciprocal, PADDED layout (0 = invalid)
__global__ __launch_bounds__(256)
void rn2_kernel(const float* __restrict__ psf, const float* __restrict__ psm,
                float* __restrict__ rn2p) {
    int g = blockIdx.x * 256 + threadIdx.x;
    if (g >= 2 * NPIX) return;
    int b = g / NPIX, m = g - b * NPIX;
    int mh = m / WW, mw = m - mh * WW;
    float sF = 0.f, sM = 0.f;
    #pragma unroll
    for (int di = -1; di <= 1; ++di) {
        if ((unsigned)(mh + di) >= HH) continue;
        #pragma unroll
        for (int dj = -1; dj <= 1; ++dj) {
            if ((unsigned)(mw + dj) >= WW) continue;
            int mm = m + di * WW + dj;
            sF += psf[b * NPIX + mm];
            sM += psm[b * NPIX + mm];
        }
    }
    float rf = 1.f / fmaxf(sqrtf(sF), 1e-12f);
    float rm = 1.f / fmaxf(sqrtf(sM), 1e-12f);
    rn2p[(size_t)b * NPP + (mh + 1) * PW + (mw + 1)] = rf * rm;
}

// ---------------------------------------------------------------------------
// Build zero-padded 82x82 copies (borders pre-zeroed by the memset).
// ---------------------------------------------------------------------------
__global__ __launch_bounds__(256)
void pad_kernel(const float* __restrict__ cf, const float* __restrict__ sf,
                const float* __restrict__ cm, const float* __restrict__ sm,
                float* __restrict__ cfp, float* __restrict__ sfp,
                float* __restrict__ cmp, float* __restrict__ smp) {
    int gid = blockIdx.x * 256 + threadIdx.x;
    if (gid >= 2 * 2 * 67 * NPIX) return;
    int pix = gid % NPIX; int t = gid / NPIX;
    int c = t % 67; t /= 67;
    int b = t & 1; int which = t >> 1;
    int h = pix / WW, w = pix - h * WW;
    int qq = (h + 1) * PW + (w + 1);
    if (which == 0) {
        if (c < 64) cfp[((size_t)b * CFE + c) * NPP + qq] = cf[((size_t)b * CFE + c) * NPIX + pix];
        else        cmp[((size_t)b * CMA + (c - 64)) * NPP + qq] = cm[((size_t)b * CMA + (c - 64)) * NPIX + pix];
    } else {
        if (c < 64) sfp[((size_t)b * CFE + c) * NPP + qq] = sf[((size_t)b * CFE + c) * NPIX + pix];
        else        smp[((size_t)b * CMA + (c - 64)) * NPP + qq] = sm[((size_t)b * CMA + (c - 64)) * NPIX + pix];
    }
}

// ---------------------------------------------------------------------------
// Fused kernel, 1024 threads (16 waves/CU). A and B staged to LDS (R7 GEMM),
// two-level-XOR-swizzled S0 buffer, sliding-window taps (8 rows x 4 d).
// ---------------------------------------------------------------------------
__global__ __launch_bounds__(1024, 4)
void fuse_kernel(const float* __restrict__ cfp, const float* __restrict__ sfp,
                 const float* __restrict__ cmp, const float* __restrict__ smp,
                 const float* __restrict__ rn2p, u64* __restrict__ pbest) {
    const int pt = blockIdx.y;
    const int b  = blockIdx.z;
    const int pstart = 83 + POUT * pt;
    const int pend   = min(pstart + POUT, 6641);
    const int pbase  = pstart - 84;
    const int dte0   = (6644 - pend) >> 5;
    const int dtemax = (13200 - pstart) >> 5;
    const int dte = dte0 + blockIdx.x;
    if (dte > dtemax) return;
    const int d0 = -6560 + 32 * dte;

    __shared__ float pool[PA * 36];              // 147456 B (staging aliases S0)

    const int tid = threadIdx.x;
    const int tp = tid & 255;                    // GEMM row group (4 rows)
    const int tg = tid >> 8;                     // GEMM d group (8 cols), 0..3
    const int wb = tid & 960;                    // wave-uniform LDS float offset
    const int swz = (((tp & 7) ^ ((tp >> 3) & 7)) << 2);   // X(row) for row=4tp+k

    const float* cfb = cfp + (size_t)b * CFE * NPP + pbase;
    const float* sfb = sfp + (size_t)b * CFE * NPP + pbase + d0;
    const float* cmb = cmp + (size_t)b * CMA * NPP + pbase;
    const float* smb = smp + (size_t)b * CMA * NPP + pbase + d0;

    float acc[4][8];
    float pdF[8][4], pdM[8][4];

    auto zacc = [&]() {
        #pragma unroll
        for (int k = 0; k < 4; ++k)
            #pragma unroll
            for (int j = 0; j < 8; ++j) acc[k][j] = 0.f;
    };

    // stage one 8-channel chunk: A rows PA, B rows BW, into dbuf half.
    // 1024 threads = 16 waves cover 1024 rows per line; 32-lane tail for B.
    auto stageF = [&](int q, int buf) {
        float* Ab = pool + buf * 16640;
        float* Bb = Ab + 8 * PA;
        const float* As = cfb + (size_t)(q * 8) * NPP;
        const float* Bs = sfb + (size_t)(q * 8) * NPP;
        #pragma unroll
        for (int cc = 0; cc < 8; ++cc) {
            gload4(As + cc * NPP + tid, Ab + cc * PA + wb);
            gload4(Bs + cc * NPP + tid, Bb + cc * BW + wb);
            if (tid < 32) gload4(Bs + cc * NPP + 1024 + tid, Bb + cc * BW + 1024);
        }
    };

    // one channel: acc[k][j] += A_lds[4tp+k] * B_lds[4tp+k + 8tg+j]
    auto gemmc = [&](const float* Ab, const float* Bb) {
        const float* Ar = Ab + 4 * tp;
        const float* Br = Bb + 4 * tp + 8 * tg;
        float a[4], bb[12];
        *(float4*)a        = ld4(Ar);
        *(float4*)bb       = ld4(Br);
        *(float4*)(bb + 4) = ld4(Br + 4);
        *(float4*)(bb + 8) = ld4(Br + 8);
        #pragma unroll
        for (int k = 0; k < 4; ++k)
            #pragma unroll
            for (int j = 0; j < 8; ++j)
                acc[k][j] = fmaf(a[k], bb[k + j], acc[k][j]);
    };

    // acc -> S0 LDS [PA rows][32 d], row stride 36, two-level XOR swizzle
    auto s0write = [&]() {
        #pragma unroll
        for (int k = 0; k < 4; ++k) {
            float* dr = pool + (4 * tp + k) * 36;
            *(float4*)(dr + ((8 * tg) ^ swz)) =
                make_float4(acc[k][0], acc[k][1], acc[k][2], acc[k][3]);
            *(float4*)(dr + ((8 * tg + 4) ^ swz)) =
                make_float4(acc[k][4], acc[k][5], acc[k][6], acc[k][7]);
        }
    };

    // sliding-window 9-tap stencil: thread (tid<856) owns 8 rows x 4 d,
    // rolling 3-row window -> 10 reads per d-group serve 24 row-taps.
    auto tapsrun = [&](float (&pd)[8][4]) {
        if (tid >= 856) return;
        const int rg = tid >> 3, dg = tid & 7;
        const int p0w = 84 + 8 * rg;
        #pragma unroll
        for (int k = 0; k < 8; ++k)
            #pragma unroll
            for (int j = 0; j < 4; ++j) pd[k][j] = 0.f;
        static const int dg3[3] = {-82, 0, 82};
        #pragma unroll
        for (int g = 0; g < 3; ++g) {
            const int rb0 = p0w + dg3[g] - 1;
            #define RD(rr) ld4(pool + (rr) * 36 + ((4 * dg) ^ (((((rr) >> 2) & 7) ^ (((rr) >> 5) & 7)) << 2)))
            float4 c0 = RD(rb0);
            float4 c1 = RD(rb0 + 1);
            #pragma unroll
            for (int k = 0; k < 8; ++k) {
                float4 c2 = RD(rb0 + 2 + k);
                pd[k][0] += c0.x + c1.x + c2.x;
                pd[k][1] += c0.y + c1.y + c2.y;
                pd[k][2] += c0.z + c1.z + c2.z;
                pd[k][3] += c0.w + c1.w + c2.w;
                c0 = c1; c1 = c2;
            }
            #undef RD
        }
    };

    // ---- feature correlation: 8 chunks of 8 channels, double-buffered
    zacc();
    stageF(0, 0);
    __syncthreads();
    #pragma unroll 1
    for (int q = 0; q < 8; ++q) {
        const int buf = q & 1;
        if (q < 7) stageF(q + 1, buf ^ 1);
        const float* Ab = pool + buf * 16640;
        const float* Bb = Ab + 8 * PA;
        #pragma unroll 2
        for (int cc = 0; cc < 8; ++cc)
            gemmc(Ab + cc * PA, Bb + cc * BW);
        __syncthreads();
    }
    s0write();
    __syncthreads();
    tapsrun(pdF);
    __syncthreads();

    // ---- mask correlation: 3 channels, single stage (A rows PA, B rows BW)
    #pragma unroll
    for (int cc = 0; cc < 3; ++cc) {
        gload4(cmb + cc * NPP + tid, pool + cc * PA + wb);
        gload4(smb + cc * NPP + tid, pool + 3 * PA + cc * BW + wb);
        if (tid < 32) gload4(smb + cc * NPP + 1024 + tid, pool + 3 * PA + cc * BW + 1024);
    }
    __syncthreads();
    zacc();
    #pragma unroll
    for (int cc = 0; cc < 3; ++cc)
        gemmc(pool + cc * PA, pool + 3 * PA + cc * BW);
    __syncthreads();
    s0write();
    __syncthreads();
    tapsrun(pdM);

    // ---- score + per-row argmax: reduce across 8 dg lanes, then atomicMax
    if (tid < 856) {
        const int rg = tid >> 3, dg = tid & 7;
        const float* rb = rn2p + (size_t)b * NPP;
        u64* pb = pbest + ((size_t)(dte & (NREG - 1)) * 2 + b) * NPIX;
        #pragma unroll
        for (int k = 0; k < 8; ++k) {
            const int row = 84 + 8 * rg + k;
            const int p = pbase + row;
            const int ph = p / PW, pw2 = p - ph * PW;
            const bool ok = (p < pend) && (ph >= 1) && (ph <= 80) && (pw2 >= 1) && (pw2 <= 80);
            u64 key = 0;
            if (ok) {
                #pragma unroll
                for (int j = 0; j < 4; ++j) {
                    int mp = p + d0 + 4 * dg + j;
                    if ((unsigned)mp >= (unsigned)NPP) continue;
                    float r2 = rb[mp];
                    if (r2 == 0.f) continue;               // pad/border -> invalid m
                    float sc = pdF[k][j] * pdM[k][j] * r2;
                    sc += 0.f;                             // -0 -> +0
                    u32 u = __float_as_uint(sc);
                    u ^= (u >> 31) ? 0xFFFFFFFFu : 0x80000000u;
                    u64 k2 = ((u64)u << 32) | (u32)~(u32)mp;
                    if (k2 > key) key = k2;
                }
            }
            u64 o;
            o = __shfl_xor(key, 1); if (o > key) key = o;
            o = __shfl_xor(key, 2); if (o > key) key = o;
            o = __shfl_xor(key, 4); if (o > key) key = o;
            if (dg == 0 && key) {
                const int n_real = (ph - 1) * 80 + (pw2 - 1);
                u64 cur = pb[n_real];                      // monotone -> safe filter
                if (key > cur) atomicMax(&pb[n_real], key);
            }
        }
    }
}

// ---------------------------------------------------------------------------
// Reduce the NREG region keys + gather the winning style patch per n.
// ---------------------------------------------------------------------------
__global__ __launch_bounds__(64)
void gather_kernel(const float* __restrict__ sf, const u64* __restrict__ pbest,
                   float* __restrict__ out) {
    int n = blockIdx.x, b = blockIdx.y;
    int lane = threadIdx.x;

    u64 key = 0;
    #pragma unroll
    for (int r = 0; r < NREG; ++r) {
        u64 k = pbest[((size_t)r * 2 + b) * NPIX + n];
        if (k > key) key = k;
    }
    int mp = (int)(~(u32)key);
    int m = 0;
    if ((unsigned)mp < (unsigned)NPP) {
        int ph = mp / PW, pw = mp - ph * PW;
        if (ph >= 1 && ph <= 80 && pw >= 1 && pw <= 80)
            m = (ph - 1) * 80 + (pw - 1);
    }
    int mh = m / WW, mw = m - mh * WW;
    const float* sfb = sf + (size_t)b * CFE * NPIX;
    float* ob = out + ((size_t)b * NPIX + n) * (size_t)KF;
    #pragma unroll
    for (int e = lane; e < KF; e += 64) {
        int c = e / 9, pos = e - c * 9;
        int di = pos / 3 - 1, dj = pos - (pos / 3) * 3 - 1;
        int h = mh + di, w = mw + dj;
        ob[e] = ((unsigned)h < HH && (unsigned)w < WW) ? sfb[c * NPIX + h * WW + w] : 0.f;
    }
}

// ---------------------------------------------------------------------------
extern "C" void kernel_launch(void* const* d_in, const int* in_sizes, int n_in,
                              void* d_out, int out_size, void* d_ws, size_t ws_size,
                              hipStream_t stream) {
    const float* cf = (const float*)d_in[0];
    const float* sf = (const float*)d_in[1];
    const float* cm = (const float*)d_in[2];
    const float* sm = (const float*)d_in[3];
    float* out = (float*)d_out;

    // ws layout (floats)
    float* psf = (float*)d_ws;                          // 2*NPIX
    float* psm = psf + 2 * NPIX;                        // 2*NPIX
    u64*  pbest = (u64*)(psm + 2 * NPIX);               // NREG*2*NPIX u64
    float* rn2p = (float*)(pbest + (size_t)NREG * 2 * NPIX);  // 2*NPP
    float* padreg = rn2p + 2 * NPP;                     // GUARD
    float* cfp = padreg + GUARD;                        // 2*64*NPP
    float* sfp = cfp + (size_t)2 * CFE * NPP + GUARD;   // 2*64*NPP
    float* cmp = sfp + (size_t)2 * CFE * NPP + GUARD;   // 2*3*NPP
    float* smp = cmp + (size_t)2 * CMA * NPP + GUARD;   // 2*3*NPP (+ trailing GUARD)

    // zero pbest + rn2p + all padded arrays + guards in one contiguous shot
    size_t zero_bytes = (size_t)NREG * 2 * NPIX * 8 +
        ((size_t)2 * NPP + (size_t)5 * GUARD +
         (size_t)4 * CFE * NPP + (size_t)4 * CMA * NPP) * 4;
    hipMemsetAsync(pbest, 0, zero_bytes, stream);

    pad_kernel<<<(2 * 2 * 67 * NPIX + 255) / 256, 256, 0, stream>>>(
        cf, sf, cm, sm, cfp, sfp, cmp, smp);
    pixsq_kernel<<<(2 * NPIX + 255) / 256, 256, 0, stream>>>(sf, sm, psf, psm);
    rn2_kernel  <<<(2 * NPIX + 255) / 256, 256, 0, stream>>>(psf, psm, rn2p);

    fuse_kernel<<<dim3(232, 8, 2), 1024, 0, stream>>>(cfp, sfp, cmp, smp, rn2p, pbest);

    gather_kernel<<<dim3(NPIX, 2), 64, 0, stream>>>(sf, pbest, out);
}

// Round 12
// 633.845 us; speedup vs baseline: 1.5969x; 1.2791x over previous
//
#include <hip/hip_runtime.h>

#define HH 80
#define WW 80
#define NPIX 6400
#define PW 82
#define NPP (PW*PW)        // 6724 padded pixels
#define CFE 64
#define CMA 3
#define KF 576
#define GUARD 1024
#define NREG 8

#define PA 1024            // S0 row window per block (incl. 84+84 halo)
#define POUT 856           // output rows per block
#define BW 1056            // B row window = PA + 32

typedef unsigned long long u64;
typedef unsigned int u32;

__device__ __forceinline__ void gload4(const float* g, float* l) {
    __builtin_amdgcn_global_load_lds((const __attribute__((address_space(1))) void*)g,
                                     (__attribute__((address_space(3))) void*)l, 4, 0, 0);
}
__device__ __forceinline__ float4 ld4(const float* p) { return *(const float4*)p; }

// ---------------------------------------------------------------------------
// per-pixel channel sum-of-squares (style side only), real grid
// ---------------------------------------------------------------------------
__global__ __launch_bounds__(256)
void pixsq_kernel(const float* __restrict__ sf, const float* __restrict__ sm,
                  float* __restrict__ psf, float* __restrict__ psm) {
    int g = blockIdx.x * 256 + threadIdx.x;
    if (g >= 2 * NPIX) return;
    int b = g / NPIX, m = g - b * NPIX;
    const float* p = sf + (size_t)b * CFE * NPIX + m;
    float a = 0.f;
    #pragma unroll 8
    for (int c = 0; c < CFE; ++c) { float v = p[c * NPIX]; a = fmaf(v, v, a); }
    const float* q = sm + (size_t)b * CMA * NPIX + m;
    float am = 0.f;
    #pragma unroll
    for (int c = 0; c < CMA; ++c) { float v = q[c * NPIX]; am = fmaf(v, v, am); }
    psf[g] = a; psm[g] = am;
}

// 9-tap masked patch-norms -> combined reciprocal, PADDED layout (0 = invalid)
__global__ __launch_bounds__(256)
void rn2_kernel(const float* __restrict__ psf, const float* __restrict__ psm,
                float* __restrict__ rn2p) {
    int g = blockIdx.x * 256 + threadIdx.x;
    if (g >= 2 * NPIX) return;
    int b = g / NPIX, m = g - b * NPIX;
    int mh = m / WW, mw = m - mh * WW;
    float sF = 0.f, sM = 0.f;
    #pragma unroll
    for (int di = -1; di <= 1; ++di) {
        if ((unsigned)(mh + di) >= HH) continue;
        #pragma unroll
        for (int dj = -1; dj <= 1; ++dj) {
            if ((unsigned)(mw + dj) >= WW) continue;
            int mm = m + di * WW + dj;
            sF += psf[b * NPIX + mm];
            sM += psm[b * NPIX + mm];
        }
    }
    float rf = 1.f / fmaxf(sqrtf(sF), 1e-12f);
    float rm = 1.f / fmaxf(sqrtf(sM), 1e-12f);
    rn2p[(size_t)b * NPP + (mh + 1) * PW + (mw + 1)] = rf * rm;
}

// ---------------------------------------------------------------------------
// Build zero-padded 82x82 copies (borders pre-zeroed by the memset).
// ---------------------------------------------------------------------------
__global__ __launch_bounds__(256)
void pad_kernel(const float* __restrict__ cf, const float* __restrict__ sf,
                const float* __restrict__ cm, const float* __restrict__ sm,
                float* __restrict__ cfp, float* __restrict__ sfp,
                float* __restrict__ cmp, float* __restrict__ smp) {
    int gid = blockIdx.x * 256 + threadIdx.x;
    if (gid >= 2 * 2 * 67 * NPIX) return;
    int pix = gid % NPIX; int t = gid / NPIX;
    int c = t % 67; t /= 67;
    int b = t & 1; int which = t >> 1;
    int h = pix / WW, w = pix - h * WW;
    int qq = (h + 1) * PW + (w + 1);
    if (which == 0) {
        if (c < 64) cfp[((size_t)b * CFE + c) * NPP + qq] = cf[((size_t)b * CFE + c) * NPIX + pix];
        else        cmp[((size_t)b * CMA + (c - 64)) * NPP + qq] = cm[((size_t)b * CMA + (c - 64)) * NPIX + pix];
    } else {
        if (c < 64) sfp[((size_t)b * CFE + c) * NPP + qq] = sf[((size_t)b * CFE + c) * NPIX + pix];
        else        smp[((size_t)b * CMA + (c - 64)) * NPP + qq] = sm[((size_t)b * CMA + (c - 64)) * NPIX + pix];
    }
}

// ---------------------------------------------------------------------------
// Fused kernel, 1024 threads (16 waves/CU). Mask phase FIRST -> pdM in regs;
// feature phase folds taps+score together so pdF never materializes.
// ---------------------------------------------------------------------------
__global__ __launch_bounds__(1024, 4)
void fuse_kernel(const float* __restrict__ cfp, const float* __restrict__ sfp,
                 const float* __restrict__ cmp, const float* __restrict__ smp,
                 const float* __restrict__ rn2p, u64* __restrict__ pbest) {
    const int pt = blockIdx.y;
    const int b  = blockIdx.z;
    const int pstart = 83 + POUT * pt;
    const int pend   = min(pstart + POUT, 6641);
    const int pbase  = pstart - 84;
    const int dte0   = (6644 - pend) >> 5;
    const int dtemax = (13200 - pstart) >> 5;
    const int dte = dte0 + blockIdx.x;
    if (dte > dtemax) return;
    const int d0 = -6560 + 32 * dte;

    __shared__ float pool[PA * 36];              // 147456 B (staging aliases S0)

    const int tid = threadIdx.x;
    const int tp = tid & 255;                    // GEMM row group (4 rows)
    const int tg = tid >> 8;                     // GEMM d group (8 cols), 0..3
    const int wb = tid & 960;                    // wave-uniform LDS float offset
    const int swz = (((tp & 7) ^ ((tp >> 3) & 7)) << 2);   // X(row) for row=4tp+k

    const float* cfb = cfp + (size_t)b * CFE * NPP + pbase;
    const float* sfb = sfp + (size_t)b * CFE * NPP + pbase + d0;
    const float* cmb = cmp + (size_t)b * CMA * NPP + pbase;
    const float* smb = smp + (size_t)b * CMA * NPP + pbase + d0;

    float acc[4][8];
    float pdM[8][4];

    auto zacc = [&]() {
        #pragma unroll
        for (int k = 0; k < 4; ++k)
            #pragma unroll
            for (int j = 0; j < 8; ++j) acc[k][j] = 0.f;
    };

    // stage one 8-channel chunk: A rows PA, B rows BW, into dbuf half.
    auto stageF = [&](int q, int buf) {
        float* Ab = pool + buf * 16640;
        float* Bb = Ab + 8 * PA;
        const float* As = cfb + (size_t)(q * 8) * NPP;
        const float* Bs = sfb + (size_t)(q * 8) * NPP;
        #pragma unroll
        for (int cc = 0; cc < 8; ++cc) {
            gload4(As + cc * NPP + tid, Ab + cc * PA + wb);
            gload4(Bs + cc * NPP + tid, Bb + cc * BW + wb);
            if (tid < 32) gload4(Bs + cc * NPP + 1024 + tid, Bb + cc * BW + 1024);
        }
    };

    // one channel: acc[k][j] += A_lds[4tp+k] * B_lds[4tp+k + 8tg+j]
    auto gemmc = [&](const float* Ab, const float* Bb) {
        const float* Ar = Ab + 4 * tp;
        const float* Br = Bb + 4 * tp + 8 * tg;
        float a[4], bb[12];
        *(float4*)a        = ld4(Ar);
        *(float4*)bb       = ld4(Br);
        *(float4*)(bb + 4) = ld4(Br + 4);
        *(float4*)(bb + 8) = ld4(Br + 8);
        #pragma unroll
        for (int k = 0; k < 4; ++k)
            #pragma unroll
            for (int j = 0; j < 8; ++j)
                acc[k][j] = fmaf(a[k], bb[k + j], acc[k][j]);
    };

    // acc -> S0 LDS [PA rows][32 d], row stride 36, two-level XOR swizzle
    auto s0write = [&]() {
        #pragma unroll
        for (int k = 0; k < 4; ++k) {
            float* dr = pool + (4 * tp + k) * 36;
            *(float4*)(dr + ((8 * tg) ^ swz)) =
                make_float4(acc[k][0], acc[k][1], acc[k][2], acc[k][3]);
            *(float4*)(dr + ((8 * tg + 4) ^ swz)) =
                make_float4(acc[k][4], acc[k][5], acc[k][6], acc[k][7]);
        }
    };

    #define RD(rr) ld4(pool + (rr) * 36 + ((4 * dg) ^ (((((rr) >> 2) & 7) ^ (((rr) >> 5) & 7)) << 2)))

    // ======================= MASK PHASE (first) =======================
    #pragma unroll
    for (int cc = 0; cc < 3; ++cc) {
        gload4(cmb + cc * NPP + tid, pool + cc * PA + wb);
        gload4(smb + cc * NPP + tid, pool + 3 * PA + cc * BW + wb);
        if (tid < 32) gload4(smb + cc * NPP + 1024 + tid, pool + 3 * PA + cc * BW + 1024);
    }
    __syncthreads();
    zacc();
    #pragma unroll
    for (int cc = 0; cc < 3; ++cc)
        gemmc(pool + cc * PA, pool + 3 * PA + cc * BW);
    __syncthreads();
    s0write();
    __syncthreads();

    // rolling-window taps -> pdM[8][4]
    if (tid < 856) {
        const int rg = tid >> 3, dg = tid & 7;
        const int p0w = 84 + 8 * rg;
        #pragma unroll
        for (int k = 0; k < 8; ++k)
            #pragma unroll
            for (int j = 0; j < 4; ++j) pdM[k][j] = 0.f;
        static const int dg3[3] = {-82, 0, 82};
        #pragma unroll
        for (int g = 0; g < 3; ++g) {
            const int rb0 = p0w + dg3[g] - 1;
            float4 c0 = RD(rb0);
            float4 c1 = RD(rb0 + 1);
            #pragma unroll
            for (int k = 0; k < 8; ++k) {
                float4 c2 = RD(rb0 + 2 + k);
                pdM[k][0] += c0.x + c1.x + c2.x;
                pdM[k][1] += c0.y + c1.y + c2.y;
                pdM[k][2] += c0.z + c1.z + c2.z;
                pdM[k][3] += c0.w + c1.w + c2.w;
                c0 = c1; c1 = c2;
            }
        }
    }
    __syncthreads();

    // ======================= FEATURE PHASE =======================
    zacc();
    stageF(0, 0);
    __syncthreads();
    #pragma unroll 1
    for (int q = 0; q < 8; ++q) {
        const int buf = q & 1;
        if (q < 7) stageF(q + 1, buf ^ 1);
        const float* Ab = pool + buf * 16640;
        const float* Bb = Ab + 8 * PA;
        #pragma unroll 2
        for (int cc = 0; cc < 8; ++cc)
            gemmc(Ab + cc * PA, Bb + cc * BW);
        __syncthreads();
    }
    s0write();
    __syncthreads();

    // fused taps + score + argmax: pdF consumed per-row, never stored
    if (tid < 856) {
        const int rg = tid >> 3, dg = tid & 7;
        const int p0w = 84 + 8 * rg;
        const int ra = p0w - 83, rbw = p0w - 1, rc = p0w + 81;
        const float* rnb = rn2p + (size_t)b * NPP;
        u64* pb = pbest + ((size_t)(dte & (NREG - 1)) * 2 + b) * NPIX;

        float4 wa0 = RD(ra),      wa1 = RD(ra + 1);
        float4 wb0 = RD(rbw),     wb1 = RD(rbw + 1);
        float4 wc0 = RD(rc),      wc1 = RD(rc + 1);
        #pragma unroll
        for (int k = 0; k < 8; ++k) {
            float4 wa2 = RD(ra + 2 + k);
            float4 wb2 = RD(rbw + 2 + k);
            float4 wc2 = RD(rc + 2 + k);
            float f0 = wa0.x + wa1.x + wa2.x + wb0.x + wb1.x + wb2.x + wc0.x + wc1.x + wc2.x;
            float f1 = wa0.y + wa1.y + wa2.y + wb0.y + wb1.y + wb2.y + wc0.y + wc1.y + wc2.y;
            float f2 = wa0.z + wa1.z + wa2.z + wb0.z + wb1.z + wb2.z + wc0.z + wc1.z + wc2.z;
            float f3 = wa0.w + wa1.w + wa2.w + wb0.w + wb1.w + wb2.w + wc0.w + wc1.w + wc2.w;
            wa0 = wa1; wa1 = wa2; wb0 = wb1; wb1 = wb2; wc0 = wc1; wc1 = wc2;

            const int row = p0w + k;
            const int p = pbase + row;
            const int ph = p / PW, pw2 = p - ph * PW;
            const bool ok = (p < pend) && (ph >= 1) && (ph <= 80) && (pw2 >= 1) && (pw2 <= 80);
            u64 key = 0;
            if (ok) {
                float pf[4] = {f0, f1, f2, f3};
                #pragma unroll
                for (int j = 0; j < 4; ++j) {
                    int mp = p + d0 + 4 * dg + j;
                    if ((unsigned)mp >= (unsigned)NPP) continue;
                    float r2 = rnb[mp];
                    if (r2 == 0.f) continue;               // pad/border -> invalid m
                    float sc = pf[j] * pdM[k][j] * r2;
                    sc += 0.f;                             // -0 -> +0
                    u32 u = __float_as_uint(sc);
                    u ^= (u >> 31) ? 0xFFFFFFFFu : 0x80000000u;
                    u64 k2 = ((u64)u << 32) | (u32)~(u32)mp;
                    if (k2 > key) key = k2;
                }
            }
            u64 o;
            o = __shfl_xor(key, 1); if (o > key) key = o;
            o = __shfl_xor(key, 2); if (o > key) key = o;
            o = __shfl_xor(key, 4); if (o > key) key = o;
            if (dg == 0 && key) {
                const int n_real = (ph - 1) * 80 + (pw2 - 1);
                u64 cur = pb[n_real];                      // monotone -> safe filter
                if (key > cur) atomicMax(&pb[n_real], key);
            }
        }
    }
    #undef RD
}

// ---------------------------------------------------------------------------
// Reduce the NREG region keys + gather the winning style patch per n.
// ---------------------------------------------------------------------------
__global__ __launch_bounds__(64)
void gather_kernel(const float* __restrict__ sf, const u64* __restrict__ pbest,
                   float* __restrict__ out) {
    int n = blockIdx.x, b = blockIdx.y;
    int lane = threadIdx.x;

    u64 key = 0;
    #pragma unroll
    for (int r = 0; r < NREG; ++r) {
        u64 k = pbest[((size_t)r * 2 + b) * NPIX + n];
        if (k > key) key = k;
    }
    int mp = (int)(~(u32)key);
    int m = 0;
    if ((unsigned)mp < (unsigned)NPP) {
        int ph = mp / PW, pw = mp - ph * PW;
        if (ph >= 1 && ph <= 80 && pw >= 1 && pw <= 80)
            m = (ph - 1) * 80 + (pw - 1);
    }
    int mh = m / WW, mw = m - mh * WW;
    const float* sfb = sf + (size_t)b * CFE * NPIX;
    float* ob = out + ((size_t)b * NPIX + n) * (size_t)KF;
    #pragma unroll
    for (int e = lane; e < KF; e += 64) {
        int c = e / 9, pos = e - c * 9;
        int di = pos / 3 - 1, dj = pos - (pos / 3) * 3 - 1;
        int h = mh + di, w = mw + dj;
        ob[e] = ((unsigned)h < HH && (unsigned)w < WW) ? sfb[c * NPIX + h * WW + w] : 0.f;
    }
}

// ---------------------------------------------------------------------------
extern "C" void kernel_launch(void* const* d_in, const int* in_sizes, int n_in,
                              void* d_out, int out_size, void* d_ws, size_t ws_size,
                              hipStream_t stream) {
    const float* cf = (const float*)d_in[0];
    const float* sf = (const float*)d_in[1];
    const float* cm = (const float*)d_in[2];
    const float* sm = (const float*)d_in[3];
    float* out = (float*)d_out;

    // ws layout (floats)
    float* psf = (float*)d_ws;                          // 2*NPIX
    float* psm = psf + 2 * NPIX;                        // 2*NPIX
    u64*  pbest = (u64*)(psm + 2 * NPIX);               // NREG*2*NPIX u64
    float* rn2p = (float*)(pbest + (size_t)NREG * 2 * NPIX);  // 2*NPP
    float* padreg = rn2p + 2 * NPP;                     // GUARD
    float* cfp = padreg + GUARD;                        // 2*64*NPP
    float* sfp = cfp + (size_t)2 * CFE * NPP + GUARD;   // 2*64*NPP
    float* cmp = sfp + (size_t)2 * CFE * NPP + GUARD;   // 2*3*NPP
    float* smp = cmp + (size_t)2 * CMA * NPP + GUARD;   // 2*3*NPP (+ trailing GUARD)

    // zero pbest + rn2p + all padded arrays + guards in one contiguous shot
    size_t zero_bytes = (size_t)NREG * 2 * NPIX * 8 +
        ((size_t)2 * NPP + (size_t)5 * GUARD +
         (size_t)4 * CFE * NPP + (size_t)4 * CMA * NPP) * 4;
    hipMemsetAsync(pbest, 0, zero_bytes, stream);

    pad_kernel<<<(2 * 2 * 67 * NPIX + 255) / 256, 256, 0, stream>>>(
        cf, sf, cm, sm, cfp, sfp, cmp, smp);
    pixsq_kernel<<<(2 * NPIX + 255) / 256, 256, 0, stream>>>(sf, sm, psf, psm);
    rn2_kernel  <<<(2 * NPIX + 255) / 256, 256, 0, stream>>>(psf, psm, rn2p);

    fuse_kernel<<<dim3(232, 8, 2), 1024, 0, stream>>>(cfp, sfp, cmp, smp, rn2p, pbest);

    gather_kernel<<<dim3(NPIX, 2), 64, 0, stream>>>(sf, pbest, out);
}